// Round 1
// baseline (952.886 us; speedup 1.0000x reference)
//
#include <hip/hip_runtime.h>

#define NH 4
#define HD 32
#define ST 64          // tokens per window (8x8)
#define CD 128         // DIM
#define IMG 102400     // U*V*H*W
#define VHW 20480      // V*H*W
#define HW_ 4096       // H*W
#define SCALE_ 0.17677669529663687f   // 32^-0.5

// ---- transpose weights into workspace: wT[c][o] (128x384), pT[c][o] (128x128)
__global__ void transpose_w_kernel(const float* __restrict__ qkv_w,
                                   const float* __restrict__ proj_w,
                                   float* __restrict__ wT,
                                   float* __restrict__ pT) {
    int i = blockIdx.x * 256 + threadIdx.x;
    if (i < 384 * 128) {
        int o = i >> 7, c = i & 127;
        wT[c * 384 + o] = qkv_w[i];
    }
    if (i < 128 * 128) {
        int o = i >> 7, c = i & 127;
        pT[c * 128 + o] = proj_w[i];
    }
}

// TR = true: weights are transposed in workspace ([c][o] contiguous in o)
// TR = false: fallback, read original layout ([o][c], stride CD in o)
template <bool TR>
__global__ __launch_bounds__(256, 1)
void win_attn_kernel(const float* __restrict__ x,
                     const float* __restrict__ wQKV,
                     const float* __restrict__ qkv_b,
                     const float* __restrict__ wP,
                     const float* __restrict__ proj_b,
                     const float* __restrict__ rpb,
                     float* __restrict__ out) {
    // 32 KB each; k_lds reused as the merged-head output tile [c][s] for proj
    __shared__ __align__(16) float k_lds[NH * ST * HD];
    __shared__ __align__(16) float v_lds[NH * ST * HD];

    const int t = threadIdx.x;
    const int h = __builtin_amdgcn_readfirstlane(t >> 6);  // wave id = head
    const int l = t & 63;                                   // lane = token

    // window id -> (b,u,v,hn,wn); order matches reshape (B,U,V,Hn,Wn)
    const int wid = blockIdx.x;
    const int wn = wid & 7, hn = (wid >> 3) & 7;
    int rem = wid >> 6;
    const int v = rem % 5; rem /= 5;
    const int u = rem % 5;
    const int b = rem / 5;

    // token l = wv*8+wh ; cyclic shift: source pixel = (win_pix - 4) mod 64
    const int hh = (((hn << 3) + (l >> 3)) - 4) & 63;
    const int ww = (((wn << 3) + (l & 7)) - 4) & 63;
    const int pix = b * (NH * HD * IMG) + u * VHW + v * HW_ + hh * 64 + ww;

    // ---------- Stage B: qkv for (token l, head h) ----------
    // out channel layout: o = h*96 + {0..31:q, 32..63:k, 64..95:v}
    float q[HD], kk[HD], vv[HD];
    {
        const float* bq = qkv_b + h * 96;
        #pragma unroll
        for (int d = 0; d < HD; ++d) {
            q[d] = bq[d]; kk[d] = bq[32 + d]; vv[d] = bq[64 + d];
        }
    }
    #pragma unroll 2
    for (int c = 0; c < CD; ++c) {
        float xv = x[pix + c * IMG];
        const float* wc = TR ? (wQKV + c * 384 + h * 96)
                             : (wQKV + h * 96 * CD + c);
        #pragma unroll
        for (int d = 0; d < HD; ++d) {
            float wq = TR ? wc[d]          : wc[d * CD];
            float wk = TR ? wc[32 + d]     : wc[(32 + d) * CD];
            float wv = TR ? wc[64 + d]     : wc[(64 + d) * CD];
            q[d]  = fmaf(xv, wq, q[d]);
            kk[d] = fmaf(xv, wk, kk[d]);
            vv[d] = fmaf(xv, wv, vv[d]);
        }
    }
    {
        float* kr = k_lds + (h * ST + l) * HD;
        float* vr = v_lds + (h * ST + l) * HD;
        #pragma unroll
        for (int d = 0; d < HD; ++d) { kr[d] = kk[d]; vr[d] = vv[d]; }
    }
    __syncthreads();

    // ---------- Stage C: attention for query row l, head h ----------
    const float* kh = k_lds + h * ST * HD;
    const float* vh = v_lds + h * ST * HD;
    const int iq = l >> 3, jq = l & 7;

    // pass 1: row max of logits (incl. bias)
    float m = -1e30f;
    for (int sk = 0; sk < ST; ++sk) {
        const float4* k4 = (const float4*)(kh + sk * HD);
        float acc = 0.f;
        #pragma unroll
        for (int d4 = 0; d4 < 8; ++d4) {
            float4 kv = k4[d4];
            acc = fmaf(q[4*d4+0], kv.x, acc);
            acc = fmaf(q[4*d4+1], kv.y, acc);
            acc = fmaf(q[4*d4+2], kv.z, acc);
            acc = fmaf(q[4*d4+3], kv.w, acc);
        }
        int ridx = (iq - (sk >> 3) + 7) * 15 + (jq - (sk & 7) + 7);
        float lg = fmaf(acc, SCALE_, rpb[ridx * 4 + h]);
        m = fmaxf(m, lg);
    }
    // pass 2: exp-sum + unnormalized PV accumulate
    float o[HD];
    #pragma unroll
    for (int d = 0; d < HD; ++d) o[d] = 0.f;
    float ssum = 0.f;
    for (int sk = 0; sk < ST; ++sk) {
        const float4* k4 = (const float4*)(kh + sk * HD);
        float acc = 0.f;
        #pragma unroll
        for (int d4 = 0; d4 < 8; ++d4) {
            float4 kv = k4[d4];
            acc = fmaf(q[4*d4+0], kv.x, acc);
            acc = fmaf(q[4*d4+1], kv.y, acc);
            acc = fmaf(q[4*d4+2], kv.z, acc);
            acc = fmaf(q[4*d4+3], kv.w, acc);
        }
        int ridx = (iq - (sk >> 3) + 7) * 15 + (jq - (sk & 7) + 7);
        float e = __expf(fmaf(acc, SCALE_, rpb[ridx * 4 + h]) - m);
        ssum += e;
        const float4* v4 = (const float4*)(vh + sk * HD);
        #pragma unroll
        for (int d4 = 0; d4 < 8; ++d4) {
            float4 vx = v4[d4];
            o[4*d4+0] = fmaf(e, vx.x, o[4*d4+0]);
            o[4*d4+1] = fmaf(e, vx.y, o[4*d4+1]);
            o[4*d4+2] = fmaf(e, vx.z, o[4*d4+2]);
            o[4*d4+3] = fmaf(e, vx.w, o[4*d4+3]);
        }
    }
    const float inv = 1.f / ssum;

    // ---------- merged-head tile [c][s] (reuse k_lds; k no longer needed) ----------
    __syncthreads();                      // all waves done reading k_lds
    float* ot = k_lds;
    #pragma unroll
    for (int d = 0; d < HD; ++d) ot[(h * HD + d) * ST + l] = o[d] * inv;
    __syncthreads();

    // ---------- Stage D: proj — token l, out channels [h*32, h*32+32) ----------
    float o2[HD];
    {
        const float* pb = proj_b + h * HD;
        #pragma unroll
        for (int j = 0; j < HD; ++j) o2[j] = pb[j];
    }
    #pragma unroll 2
    for (int c = 0; c < CD; ++c) {
        float xv = ot[c * ST + l];
        const float* pc = TR ? (wP + c * CD + h * HD) : (wP + h * HD * CD + c);
        #pragma unroll
        for (int j = 0; j < HD; ++j) {
            float wv = TR ? pc[j] : pc[j * CD];
            o2[j] = fmaf(xv, wv, o2[j]);
        }
    }

    // ---------- Stage E: scatter (reverse shift == same pixel mapping) ----------
    float* ob = out + pix;
    #pragma unroll
    for (int j = 0; j < HD; ++j) ob[(h * HD + j) * IMG] = o2[j];
}

extern "C" void kernel_launch(void* const* d_in, const int* in_sizes, int n_in,
                              void* d_out, int out_size, void* d_ws, size_t ws_size,
                              hipStream_t stream) {
    const float* x      = (const float*)d_in[0];
    const float* qkv_w  = (const float*)d_in[1];
    const float* qkv_b  = (const float*)d_in[2];
    const float* proj_w = (const float*)d_in[3];
    const float* proj_b = (const float*)d_in[4];
    const float* rpb    = (const float*)d_in[5];
    float* out = (float*)d_out;

    const int nW = 2 * 5 * 5 * 8 * 8;  // 3200 windows

    const size_t need = (size_t)(384 * 128 + 128 * 128) * sizeof(float);
    if (ws_size >= need) {
        float* wT = (float*)d_ws;            // 384*128
        float* pT = wT + 384 * 128;          // 128*128
        transpose_w_kernel<<<192, 256, 0, stream>>>(qkv_w, proj_w, wT, pT);
        win_attn_kernel<true><<<nW, 256, 0, stream>>>(x, wT, qkv_b, pT, proj_b, rpb, out);
    } else {
        win_attn_kernel<false><<<nW, 256, 0, stream>>>(x, qkv_w, qkv_b, proj_w, proj_b, rpb, out);
    }
}

// Round 2
// 354.708 us; speedup vs baseline: 2.6864x; 2.6864x over previous
//
#include <hip/hip_runtime.h>

#define NH 4
#define HD 32
#define ST 64          // tokens per window (8x8)
#define CD 128         // DIM
#define IMG 102400     // U*V*H*W
#define VHW 20480      // V*H*W
#define HW_ 4096       // H*W
#define SCALE_ 0.17677669529663687f   // 32^-0.5

typedef __attribute__((ext_vector_type(8))) short bf16x8;
typedef __attribute__((ext_vector_type(4))) float f32x4;

__device__ __forceinline__ short f2bf(float f) {
    unsigned int u = __float_as_uint(f);
    u = (u + 0x7FFF + ((u >> 16) & 1)) >> 16;   // RNE
    return (short)u;
}

// ---- fp32 -> bf16 weight conversion into workspace
__global__ void cvt_w_kernel(const float* __restrict__ qkv_w,
                             const float* __restrict__ proj_w,
                             short* __restrict__ wq,
                             short* __restrict__ wp) {
    int i = blockIdx.x * 256 + threadIdx.x;   // 65536 threads
    if (i < 49152) wq[i] = f2bf(qkv_w[i]);
    else           wp[i - 49152] = f2bf(proj_w[i - 49152]);
}

// LDS map (shorts; total 32256 shorts = 63 KB):
//  X      [0, 2560)                 64 x 40   (row pad 40 for 16B-aligned frags)
//  head h chunk at 2560 + h*5120:
//    Q_h  [+0,    +2560)            64 x 40
//    K_h  [+2560, +5120)            64 x 40
//    P_h aliases [+0, +4608)        64 x 72   (Q/K dead when written; in-wave only)
//  V_t    [23040, 32256)            per head 32 x 72 (d-major)
//  O   aliases [0, 8704)            64 x 136  (after PV barrier)
//  F fp32 aliases [0, 16640 shorts) 128 x 65 floats (after proj barrier)

__global__ __launch_bounds__(256, 2)
void win_attn_mfma(const float* __restrict__ x,
                   const short* __restrict__ wq,     // bf16 [384][128]
                   const float* __restrict__ qkv_b,
                   const short* __restrict__ wp,     // bf16 [128][128]
                   const float* __restrict__ proj_b,
                   const float* __restrict__ rpb,
                   float* __restrict__ out) {
    __shared__ __align__(16) short smem[32256];

    const int t    = threadIdx.x;
    const int h    = __builtin_amdgcn_readfirstlane(t >> 6);  // wave = head
    const int ln   = t & 15;
    const int quad = (t >> 4) & 3;
    const int tok  = t & 63;

    // window id -> (b,u,v,hn,wn)
    const int wid = blockIdx.x;
    const int wn = wid & 7, hn = (wid >> 3) & 7;
    int rem = wid >> 6;
    const int v = rem % 5; rem /= 5;
    const int u = rem % 5;
    const int b = rem / 5;

    // cyclic shift: source pixel = (win_pix - 4) mod 64 (same map for gather & scatter)
    const int hh = (((hn << 3) + (tok >> 3)) - 4) & 63;
    const int ww = (((wn << 3) + (tok & 7)) - 4) & 63;
    const long pix = (long)b * (CD * IMG) + u * VHW + v * HW_ + hh * 64 + ww;

    short* X  = smem;
    short* Qh = smem + 2560 + h * 5120;
    short* Kh = Qh + 2560;
    short* Ph = Qh;                       // aliases Q_h + part of K_h (in-wave)
    short* Vh = smem + 23040 + h * 2304;  // [32][72]

    // ================= QKV GEMM: (64x128) @ (128x384)^T =================
    f32x4 acc[6][4];
    #pragma unroll
    for (int n = 0; n < 6; ++n)
        #pragma unroll
        for (int mt = 0; mt < 4; ++mt) acc[n][mt] = (f32x4){0.f, 0.f, 0.f, 0.f};

    for (int kh = 0; kh < 4; ++kh) {      // 4 K-quarters of 32 channels
        __syncthreads();
        {   // stage: each thread loads 8 channels of its token, once per block
            const int cbase = kh * 32 + h * 8;
            float f[8];
            #pragma unroll
            for (int j = 0; j < 8; ++j) f[j] = x[pix + (long)(cbase + j) * IMG];
            bf16x8 pk;
            #pragma unroll
            for (int j = 0; j < 8; ++j) pk[j] = f2bf(f[j]);
            *(bf16x8*)(X + tok * 40 + h * 8) = pk;
        }
        __syncthreads();
        bf16x8 af[4];
        #pragma unroll
        for (int mt = 0; mt < 4; ++mt)
            af[mt] = *(const bf16x8*)(X + (mt * 16 + ln) * 40 + quad * 8);
        #pragma unroll
        for (int n = 0; n < 6; ++n) {
            bf16x8 bf = *(const bf16x8*)(wq + (h * 96 + n * 16 + ln) * 128 + kh * 32 + quad * 8);
            #pragma unroll
            for (int mt = 0; mt < 4; ++mt)
                acc[n][mt] = __builtin_amdgcn_mfma_f32_16x16x32_bf16(af[mt], bf, acc[n][mt], 0, 0, 0);
        }
    }

    // D-tiles -> LDS: Q (scaled), K token-major; V d-major (transposed)
    #pragma unroll
    for (int n = 0; n < 6; ++n) {
        const float bias = qkv_b[h * 96 + n * 16 + ln];
        #pragma unroll
        for (int mt = 0; mt < 4; ++mt)
            #pragma unroll
            for (int r = 0; r < 4; ++r) {
                const float val = acc[n][mt][r] + bias;
                const int tk = mt * 16 + quad * 4 + r;
                if (n < 2)      Qh[tk * 40 + n * 16 + ln] = f2bf(val * SCALE_);
                else if (n < 4) Kh[tk * 40 + (n - 2) * 16 + ln] = f2bf(val);
                else            Vh[((n - 4) * 16 + ln) * 72 + tk] = f2bf(val);
            }
    }
    // Q/K/V/P are strictly per-head, per-wave: no barrier needed until O overwrite.

    // ================= S = Q K^T (64x64, K=32) =================
    bf16x8 aq[4], bk[4];
    #pragma unroll
    for (int mt = 0; mt < 4; ++mt) aq[mt] = *(const bf16x8*)(Qh + (mt * 16 + ln) * 40 + quad * 8);
    #pragma unroll
    for (int nt = 0; nt < 4; ++nt) bk[nt] = *(const bf16x8*)(Kh + (nt * 16 + ln) * 40 + quad * 8);
    f32x4 s[4][4];
    #pragma unroll
    for (int mt = 0; mt < 4; ++mt)
        #pragma unroll
        for (int nt = 0; nt < 4; ++nt) {
            f32x4 z = (f32x4){0.f, 0.f, 0.f, 0.f};
            s[mt][nt] = __builtin_amdgcn_mfma_f32_16x16x32_bf16(aq[mt], bk[nt], z, 0, 0, 0);
        }

    // relative-position bias
    #pragma unroll
    for (int nt = 0; nt < 4; ++nt) {
        const int kcol = nt * 16 + ln;
        const int ik = kcol >> 3, jk = kcol & 7;
        #pragma unroll
        for (int mt = 0; mt < 4; ++mt)
            #pragma unroll
            for (int r = 0; r < 4; ++r) {
                const int q = mt * 16 + quad * 4 + r;
                const int ridx = ((q >> 3) - ik + 7) * 15 + ((q & 7) - jk + 7);
                s[mt][nt][r] += rpb[ridx * 4 + h];
            }
    }

    // softmax rows: row=(mt,r); cols span nt x 16 lanes of the quad
    float inv[4][4];
    #pragma unroll
    for (int mt = 0; mt < 4; ++mt)
        #pragma unroll
        for (int r = 0; r < 4; ++r) {
            float m = fmaxf(fmaxf(s[mt][0][r], s[mt][1][r]), fmaxf(s[mt][2][r], s[mt][3][r]));
            #pragma unroll
            for (int msk = 1; msk < 16; msk <<= 1) m = fmaxf(m, __shfl_xor(m, msk, 64));
            float sum = 0.f;
            #pragma unroll
            for (int nt = 0; nt < 4; ++nt) {
                float e = __expf(s[mt][nt][r] - m);
                s[mt][nt][r] = e;
                sum += e;
            }
            #pragma unroll
            for (int msk = 1; msk < 16; msk <<= 1) sum += __shfl_xor(sum, msk, 64);
            inv[mt][r] = 1.f / sum;
            const int q = mt * 16 + quad * 4 + r;
            #pragma unroll
            for (int nt = 0; nt < 4; ++nt)
                Ph[q * 72 + nt * 16 + ln] = f2bf(s[mt][nt][r]);   // unnormalized P
        }

    // ================= O = P V (64x32, K=64) =================
    f32x4 oa[4][2];
    #pragma unroll
    for (int mt = 0; mt < 4; ++mt)
        #pragma unroll
        for (int nt = 0; nt < 2; ++nt) oa[mt][nt] = (f32x4){0.f, 0.f, 0.f, 0.f};
    #pragma unroll
    for (int kt = 0; kt < 2; ++kt) {
        bf16x8 ap[4], bv[2];
        #pragma unroll
        for (int mt = 0; mt < 4; ++mt)
            ap[mt] = *(const bf16x8*)(Ph + (mt * 16 + ln) * 72 + kt * 32 + quad * 8);
        #pragma unroll
        for (int nt = 0; nt < 2; ++nt)
            bv[nt] = *(const bf16x8*)(Vh + (nt * 16 + ln) * 72 + kt * 32 + quad * 8);
        #pragma unroll
        for (int mt = 0; mt < 4; ++mt)
            #pragma unroll
            for (int nt = 0; nt < 2; ++nt)
                oa[mt][nt] = __builtin_amdgcn_mfma_f32_16x16x32_bf16(ap[mt], bv[nt], oa[mt][nt], 0, 0, 0);
    }

    __syncthreads();              // everyone done with P/V before O overwrites region
    short* O = smem;              // [64][136]
    #pragma unroll
    for (int mt = 0; mt < 4; ++mt)
        #pragma unroll
        for (int nt = 0; nt < 2; ++nt)
            #pragma unroll
            for (int r = 0; r < 4; ++r)
                O[(mt * 16 + quad * 4 + r) * 136 + h * 32 + nt * 16 + ln] =
                    f2bf(oa[mt][nt][r] * inv[mt][r]);
    __syncthreads();

    // ================= proj: (64x128) @ (128x128)^T =================
    f32x4 pa[4][2];
    #pragma unroll
    for (int mt = 0; mt < 4; ++mt)
        #pragma unroll
        for (int nt = 0; nt < 2; ++nt) pa[mt][nt] = (f32x4){0.f, 0.f, 0.f, 0.f};
    #pragma unroll
    for (int kt = 0; kt < 4; ++kt) {
        bf16x8 ao[4], bw[2];
        #pragma unroll
        for (int mt = 0; mt < 4; ++mt)
            ao[mt] = *(const bf16x8*)(O + (mt * 16 + ln) * 136 + kt * 32 + quad * 8);
        #pragma unroll
        for (int nt = 0; nt < 2; ++nt)
            bw[nt] = *(const bf16x8*)(wp + (h * 32 + nt * 16 + ln) * 128 + kt * 32 + quad * 8);
        #pragma unroll
        for (int mt = 0; mt < 4; ++mt)
            #pragma unroll
            for (int nt = 0; nt < 2; ++nt)
                pa[mt][nt] = __builtin_amdgcn_mfma_f32_16x16x32_bf16(ao[mt], bw[nt], pa[mt][nt], 0, 0, 0);
    }
    float pb[2];
    #pragma unroll
    for (int nt = 0; nt < 2; ++nt) pb[nt] = proj_b[h * 32 + nt * 16 + ln];

    __syncthreads();              // all proj A-frag reads done before F overwrites
    float* F = (float*)smem;      // [128][65]
    #pragma unroll
    for (int mt = 0; mt < 4; ++mt)
        #pragma unroll
        for (int nt = 0; nt < 2; ++nt)
            #pragma unroll
            for (int r = 0; r < 4; ++r)
                F[(h * 32 + nt * 16 + ln) * 65 + mt * 16 + quad * 4 + r] = pa[mt][nt][r] + pb[nt];
    __syncthreads();

    // scatter: thread t stores 32 channels of its token (reverse shift == same pix)
    #pragma unroll 4
    for (int j = 0; j < 32; ++j) {
        const int c = h * 32 + j;
        out[pix + (long)c * IMG] = F[c * 65 + tok];
    }
}

// ---------- round-1 fp32 fallback (only if workspace is too small) ----------
__global__ __launch_bounds__(256, 1)
void win_attn_fallback(const float* __restrict__ x,
                       const float* __restrict__ wQKV,
                       const float* __restrict__ qkv_b,
                       const float* __restrict__ wP,
                       const float* __restrict__ proj_b,
                       const float* __restrict__ rpb,
                       float* __restrict__ out) {
    __shared__ __align__(16) float k_lds[NH * ST * HD];
    __shared__ __align__(16) float v_lds[NH * ST * HD];
    const int t = threadIdx.x;
    const int h = __builtin_amdgcn_readfirstlane(t >> 6);
    const int l = t & 63;
    const int wid = blockIdx.x;
    const int wn = wid & 7, hn = (wid >> 3) & 7;
    int rem = wid >> 6;
    const int v = rem % 5; rem /= 5;
    const int u = rem % 5;
    const int b = rem / 5;
    const int hh = (((hn << 3) + (l >> 3)) - 4) & 63;
    const int ww = (((wn << 3) + (l & 7)) - 4) & 63;
    const int pix = b * (NH * HD * IMG) + u * VHW + v * HW_ + hh * 64 + ww;
    float q[HD], kk[HD], vv[HD];
    const float* bq = qkv_b + h * 96;
    #pragma unroll
    for (int d = 0; d < HD; ++d) { q[d] = bq[d]; kk[d] = bq[32 + d]; vv[d] = bq[64 + d]; }
    for (int c = 0; c < CD; ++c) {
        float xv = x[pix + c * IMG];
        const float* wc = wQKV + h * 96 * CD + c;
        #pragma unroll
        for (int d = 0; d < HD; ++d) {
            q[d]  = fmaf(xv, wc[d * CD], q[d]);
            kk[d] = fmaf(xv, wc[(32 + d) * CD], kk[d]);
            vv[d] = fmaf(xv, wc[(64 + d) * CD], vv[d]);
        }
    }
    float* kr = k_lds + (h * ST + l) * HD;
    float* vr = v_lds + (h * ST + l) * HD;
    #pragma unroll
    for (int d = 0; d < HD; ++d) { kr[d] = kk[d]; vr[d] = vv[d]; }
    __syncthreads();
    const float* kh2 = k_lds + h * ST * HD;
    const float* vh2 = v_lds + h * ST * HD;
    const int iq = l >> 3, jq = l & 7;
    float m = -1e30f;
    for (int sk = 0; sk < ST; ++sk) {
        const float* kp = kh2 + sk * HD;
        float a2 = 0.f;
        #pragma unroll
        for (int d = 0; d < HD; ++d) a2 = fmaf(q[d], kp[d], a2);
        int ridx = (iq - (sk >> 3) + 7) * 15 + (jq - (sk & 7) + 7);
        m = fmaxf(m, fmaf(a2, SCALE_, rpb[ridx * 4 + h]));
    }
    float o[HD];
    #pragma unroll
    for (int d = 0; d < HD; ++d) o[d] = 0.f;
    float ssum = 0.f;
    for (int sk = 0; sk < ST; ++sk) {
        const float* kp = kh2 + sk * HD;
        float a2 = 0.f;
        #pragma unroll
        for (int d = 0; d < HD; ++d) a2 = fmaf(q[d], kp[d], a2);
        int ridx = (iq - (sk >> 3) + 7) * 15 + (jq - (sk & 7) + 7);
        float e = __expf(fmaf(a2, SCALE_, rpb[ridx * 4 + h]) - m);
        ssum += e;
        const float* vp = vh2 + sk * HD;
        #pragma unroll
        for (int d = 0; d < HD; ++d) o[d] = fmaf(e, vp[d], o[d]);
    }
    const float inv = 1.f / ssum;
    __syncthreads();
    float* ot = k_lds;
    #pragma unroll
    for (int d = 0; d < HD; ++d) ot[(h * HD + d) * ST + l] = o[d] * inv;
    __syncthreads();
    float o2[HD];
    const float* pb2 = proj_b + h * HD;
    #pragma unroll
    for (int j = 0; j < HD; ++j) o2[j] = pb2[j];
    for (int c = 0; c < CD; ++c) {
        float xv = ot[c * ST + l];
        const float* pc = wP + h * HD * CD + c;
        #pragma unroll
        for (int j = 0; j < HD; ++j) o2[j] = fmaf(xv, pc[j * CD], o2[j]);
    }
    float* ob = out + pix;
    #pragma unroll
    for (int j = 0; j < HD; ++j) ob[(h * HD + j) * IMG] = o2[j];
}

extern "C" void kernel_launch(void* const* d_in, const int* in_sizes, int n_in,
                              void* d_out, int out_size, void* d_ws, size_t ws_size,
                              hipStream_t stream) {
    const float* x      = (const float*)d_in[0];
    const float* qkv_w  = (const float*)d_in[1];
    const float* qkv_b  = (const float*)d_in[2];
    const float* proj_w = (const float*)d_in[3];
    const float* proj_b = (const float*)d_in[4];
    const float* rpb    = (const float*)d_in[5];
    float* out = (float*)d_out;

    const int nW = 2 * 5 * 5 * 8 * 8;  // 3200 windows
    const size_t need = (size_t)(49152 + 16384) * sizeof(short);  // 128 KB

    if (ws_size >= need) {
        short* wq = (short*)d_ws;
        short* wp = wq + 49152;
        cvt_w_kernel<<<256, 256, 0, stream>>>(qkv_w, proj_w, wq, wp);
        win_attn_mfma<<<nW, 256, 0, stream>>>(x, wq, qkv_b, wp, proj_b, rpb, out);
    } else {
        win_attn_fallback<<<nW, 256, 0, stream>>>(x, qkv_w, qkv_b, proj_w, proj_b, rpb, out);
    }
}

// Round 3
// 314.443 us; speedup vs baseline: 3.0304x; 1.1281x over previous
//
#include <hip/hip_runtime.h>

#define NH 4
#define HD 32
#define ST 64          // tokens per window (8x8)
#define CD 128         // DIM
#define IMG 102400     // U*V*H*W
#define VHW 20480      // V*H*W
#define HW_ 4096       // H*W
#define SCALE_ 0.17677669529663687f   // 32^-0.5

typedef __attribute__((ext_vector_type(8))) short bf16x8;
typedef __attribute__((ext_vector_type(4))) float f32x4;

__device__ __forceinline__ short f2bf(float f) {
    unsigned int u = __float_as_uint(f);
    u = (u + 0x7FFF + ((u >> 16) & 1)) >> 16;   // RNE
    return (short)u;
}

// ---- fp32 -> bf16 weight conversion into workspace
__global__ void cvt_w_kernel(const float* __restrict__ qkv_w,
                             const float* __restrict__ proj_w,
                             short* __restrict__ wq,
                             short* __restrict__ wp) {
    int i = blockIdx.x * 256 + threadIdx.x;   // 65536 threads
    if (i < 49152) wq[i] = f2bf(qkv_w[i]);
    else           wp[i - 49152] = f2bf(proj_w[i - 49152]);
}

// LDS map (shorts; total 38400 shorts = 75 KB):
//  X      [0, 8704)                 64 x 136  (tok-major, 128 ch + pad 8)
//  head h chunk at 8704 + h*5120:
//    Q_h  [+0,    +2560)            64 x 40
//    K_h  [+2560, +5120)            64 x 40
//    P_h aliases [+0, +4608)        64 x 72   (Q/K dead when written; in-wave only)
//  V     [29184, 38400)             per head 32 x 72 (d-major)
//  O   aliases [0, 8704)            64 x 136  (after barrier; X dead)
//  F fp32 aliases [0, 16640 shorts) 128 x 65 floats (after proj-read barrier)

__global__ __launch_bounds__(256, 2)
void win_attn_mfma(const float* __restrict__ x,
                   const short* __restrict__ wq,     // bf16 [384][128]
                   const float* __restrict__ qkv_b,
                   const short* __restrict__ wp,     // bf16 [128][128]
                   const float* __restrict__ proj_b,
                   const float* __restrict__ rpb,
                   float* __restrict__ out) {
    __shared__ __align__(16) short smem[38400];

    const int t    = threadIdx.x;
    const int h    = __builtin_amdgcn_readfirstlane(t >> 6);  // wave = head
    const int ln   = t & 15;
    const int quad = (t >> 4) & 3;
    const int tok  = t & 63;

    // XCD swizzle: round-robin dispatch (xcd = blockIdx % 8) -> give each XCD
    // 400 CONTIGUOUS logical windows so the two windows sharing each 64B line
    // (adjacent wn) hit the same per-XCD L2 -> half-line fetch/write dedup.
    const int wid = (blockIdx.x & 7) * 400 + (blockIdx.x >> 3);

    // window id -> (b,u,v,hn,wn)
    const int wn = wid & 7, hn = (wid >> 3) & 7;
    int rem = wid >> 6;
    const int v = rem % 5; rem /= 5;
    const int u = rem % 5;
    const int b = rem / 5;

    // cyclic shift: source pixel = (win_pix - 4) mod 64 (same map for gather & scatter)
    const int hh = (((hn << 3) + (tok >> 3)) - 4) & 63;
    const int ww = (((wn << 3) + (tok & 7)) - 4) & 63;
    const long pix = (long)b * (CD * IMG) + u * VHW + v * HW_ + hh * 64 + ww;

    short* X  = smem;                      // [64][136]
    short* Qh = smem + 8704 + h * 5120;
    short* Kh = Qh + 2560;
    short* Ph = Qh;                        // aliases Q_h/K_h (in-wave only)
    short* Vh = smem + 29184 + h * 2304;   // [32][72]

    // ---- hoisted gather: ALL 32 channel loads in flight at once ----
    float xr[32];
    #pragma unroll
    for (int kh = 0; kh < 4; ++kh)
        #pragma unroll
        for (int j = 0; j < 8; ++j)
            xr[kh * 8 + j] = x[pix + (long)(kh * 32 + h * 8 + j) * IMG];
    #pragma unroll
    for (int kh = 0; kh < 4; ++kh) {
        bf16x8 pk;
        #pragma unroll
        for (int j = 0; j < 8; ++j) pk[j] = f2bf(xr[kh * 8 + j]);
        *(bf16x8*)(X + tok * 136 + kh * 32 + h * 8) = pk;
    }
    __syncthreads();                       // barrier 1: X ready

    // ================= QKV GEMM: (64x128) @ (128x384)^T =================
    f32x4 acc[6][4];
    #pragma unroll
    for (int n = 0; n < 6; ++n)
        #pragma unroll
        for (int mt = 0; mt < 4; ++mt) acc[n][mt] = (f32x4){0.f, 0.f, 0.f, 0.f};

    #pragma unroll
    for (int kh = 0; kh < 4; ++kh) {
        bf16x8 af[4];
        #pragma unroll
        for (int mt = 0; mt < 4; ++mt)
            af[mt] = *(const bf16x8*)(X + (mt * 16 + ln) * 136 + kh * 32 + quad * 8);
        #pragma unroll
        for (int n = 0; n < 6; ++n) {
            bf16x8 bf = *(const bf16x8*)(wq + (h * 96 + n * 16 + ln) * 128 + kh * 32 + quad * 8);
            #pragma unroll
            for (int mt = 0; mt < 4; ++mt)
                acc[n][mt] = __builtin_amdgcn_mfma_f32_16x16x32_bf16(af[mt], bf, acc[n][mt], 0, 0, 0);
        }
    }

    // D-tiles -> LDS: Q (scaled), K token-major; V d-major (transposed)
    #pragma unroll
    for (int n = 0; n < 6; ++n) {
        const float bias = qkv_b[h * 96 + n * 16 + ln];
        #pragma unroll
        for (int mt = 0; mt < 4; ++mt)
            #pragma unroll
            for (int r = 0; r < 4; ++r) {
                const float val = acc[n][mt][r] + bias;
                const int tk = mt * 16 + quad * 4 + r;
                if (n < 2)      Qh[tk * 40 + n * 16 + ln] = f2bf(val * SCALE_);
                else if (n < 4) Kh[tk * 40 + (n - 2) * 16 + ln] = f2bf(val);
                else            Vh[((n - 4) * 16 + ln) * 72 + tk] = f2bf(val);
            }
    }
    // Q/K/V/P are strictly per-head, per-wave: no barrier until O overwrites X.

    // ================= S = Q K^T (64x64, K=32) =================
    bf16x8 aq[4], bk[4];
    #pragma unroll
    for (int mt = 0; mt < 4; ++mt) aq[mt] = *(const bf16x8*)(Qh + (mt * 16 + ln) * 40 + quad * 8);
    #pragma unroll
    for (int nt = 0; nt < 4; ++nt) bk[nt] = *(const bf16x8*)(Kh + (nt * 16 + ln) * 40 + quad * 8);
    f32x4 s[4][4];
    #pragma unroll
    for (int mt = 0; mt < 4; ++mt)
        #pragma unroll
        for (int nt = 0; nt < 4; ++nt) {
            f32x4 z = (f32x4){0.f, 0.f, 0.f, 0.f};
            s[mt][nt] = __builtin_amdgcn_mfma_f32_16x16x32_bf16(aq[mt], bk[nt], z, 0, 0, 0);
        }

    // relative-position bias
    #pragma unroll
    for (int nt = 0; nt < 4; ++nt) {
        const int kcol = nt * 16 + ln;
        const int ik = kcol >> 3, jk = kcol & 7;
        #pragma unroll
        for (int mt = 0; mt < 4; ++mt)
            #pragma unroll
            for (int r = 0; r < 4; ++r) {
                const int q = mt * 16 + quad * 4 + r;
                const int ridx = ((q >> 3) - ik + 7) * 15 + ((q & 7) - jk + 7);
                s[mt][nt][r] += rpb[ridx * 4 + h];
            }
    }

    // softmax rows: row=(mt,r); cols span nt x 16 lanes of the quad
    float inv[4][4];
    #pragma unroll
    for (int mt = 0; mt < 4; ++mt)
        #pragma unroll
        for (int r = 0; r < 4; ++r) {
            float m = fmaxf(fmaxf(s[mt][0][r], s[mt][1][r]), fmaxf(s[mt][2][r], s[mt][3][r]));
            #pragma unroll
            for (int msk = 1; msk < 16; msk <<= 1) m = fmaxf(m, __shfl_xor(m, msk, 64));
            float sum = 0.f;
            #pragma unroll
            for (int nt = 0; nt < 4; ++nt) {
                float e = __expf(s[mt][nt][r] - m);
                s[mt][nt][r] = e;
                sum += e;
            }
            #pragma unroll
            for (int msk = 1; msk < 16; msk <<= 1) sum += __shfl_xor(sum, msk, 64);
            inv[mt][r] = 1.f / sum;
            const int q = mt * 16 + quad * 4 + r;
            #pragma unroll
            for (int nt = 0; nt < 4; ++nt)
                Ph[q * 72 + nt * 16 + ln] = f2bf(s[mt][nt][r]);   // unnormalized P
        }

    // ================= O = P V (64x32, K=64) =================
    f32x4 oa[4][2];
    #pragma unroll
    for (int mt = 0; mt < 4; ++mt)
        #pragma unroll
        for (int nt = 0; nt < 2; ++nt) oa[mt][nt] = (f32x4){0.f, 0.f, 0.f, 0.f};
    #pragma unroll
    for (int kt = 0; kt < 2; ++kt) {
        bf16x8 ap[4], bv[2];
        #pragma unroll
        for (int mt = 0; mt < 4; ++mt)
            ap[mt] = *(const bf16x8*)(Ph + (mt * 16 + ln) * 72 + kt * 32 + quad * 8);
        #pragma unroll
        for (int nt = 0; nt < 2; ++nt)
            bv[nt] = *(const bf16x8*)(Vh + (nt * 16 + ln) * 72 + kt * 32 + quad * 8);
        #pragma unroll
        for (int mt = 0; mt < 4; ++mt)
            #pragma unroll
            for (int nt = 0; nt < 2; ++nt)
                oa[mt][nt] = __builtin_amdgcn_mfma_f32_16x16x32_bf16(ap[mt], bv[nt], oa[mt][nt], 0, 0, 0);
    }

    __syncthreads();              // barrier 2: all waves past X reads before O overwrite
    short* O = smem;              // [64][136]
    #pragma unroll
    for (int mt = 0; mt < 4; ++mt)
        #pragma unroll
        for (int nt = 0; nt < 2; ++nt)
            #pragma unroll
            for (int r = 0; r < 4; ++r)
                O[(mt * 16 + quad * 4 + r) * 136 + h * 32 + nt * 16 + ln] =
                    f2bf(oa[mt][nt][r] * inv[mt][r]);
    __syncthreads();              // barrier 3: O ready

    // ================= proj: (64x128) @ (128x128)^T =================
    f32x4 pa[4][2];
    #pragma unroll
    for (int mt = 0; mt < 4; ++mt)
        #pragma unroll
        for (int nt = 0; nt < 2; ++nt) pa[mt][nt] = (f32x4){0.f, 0.f, 0.f, 0.f};
    #pragma unroll
    for (int kt = 0; kt < 4; ++kt) {
        bf16x8 ao[4], bw[2];
        #pragma unroll
        for (int mt = 0; mt < 4; ++mt)
            ao[mt] = *(const bf16x8*)(O + (mt * 16 + ln) * 136 + kt * 32 + quad * 8);
        #pragma unroll
        for (int nt = 0; nt < 2; ++nt)
            bw[nt] = *(const bf16x8*)(wp + (h * 32 + nt * 16 + ln) * 128 + kt * 32 + quad * 8);
        #pragma unroll
        for (int mt = 0; mt < 4; ++mt)
            #pragma unroll
            for (int nt = 0; nt < 2; ++nt)
                pa[mt][nt] = __builtin_amdgcn_mfma_f32_16x16x32_bf16(ao[mt], bw[nt], pa[mt][nt], 0, 0, 0);
    }
    float pb[2];
    #pragma unroll
    for (int nt = 0; nt < 2; ++nt) pb[nt] = proj_b[h * 32 + nt * 16 + ln];

    __syncthreads();              // barrier 4: all proj A-frag reads done before F overwrites
    float* F = (float*)smem;      // [128][65]
    #pragma unroll
    for (int mt = 0; mt < 4; ++mt)
        #pragma unroll
        for (int nt = 0; nt < 2; ++nt)
            #pragma unroll
            for (int r = 0; r < 4; ++r)
                F[(h * 32 + nt * 16 + ln) * 65 + mt * 16 + quad * 4 + r] = pa[mt][nt][r] + pb[nt];
    __syncthreads();              // barrier 5: F ready

    // scatter: thread t stores 32 channels of its token (reverse shift == same pix)
    #pragma unroll
    for (int j = 0; j < 32; ++j) {
        const int c = h * 32 + j;
        out[pix + (long)c * IMG] = F[c * 65 + tok];
    }
}

// ---------- fp32 fallback (only if workspace is too small) ----------
__global__ __launch_bounds__(256, 1)
void win_attn_fallback(const float* __restrict__ x,
                       const float* __restrict__ wQKV,
                       const float* __restrict__ qkv_b,
                       const float* __restrict__ wP,
                       const float* __restrict__ proj_b,
                       const float* __restrict__ rpb,
                       float* __restrict__ out) {
    __shared__ __align__(16) float k_lds[NH * ST * HD];
    __shared__ __align__(16) float v_lds[NH * ST * HD];
    const int t = threadIdx.x;
    const int h = __builtin_amdgcn_readfirstlane(t >> 6);
    const int l = t & 63;
    const int wid = blockIdx.x;
    const int wn = wid & 7, hn = (wid >> 3) & 7;
    int rem = wid >> 6;
    const int v = rem % 5; rem /= 5;
    const int u = rem % 5;
    const int b = rem / 5;
    const int hh = (((hn << 3) + (l >> 3)) - 4) & 63;
    const int ww = (((wn << 3) + (l & 7)) - 4) & 63;
    const int pix = b * (NH * HD * IMG) + u * VHW + v * HW_ + hh * 64 + ww;
    float q[HD], kk[HD], vv[HD];
    const float* bq = qkv_b + h * 96;
    #pragma unroll
    for (int d = 0; d < HD; ++d) { q[d] = bq[d]; kk[d] = bq[32 + d]; vv[d] = bq[64 + d]; }
    for (int c = 0; c < CD; ++c) {
        float xv = x[pix + c * IMG];
        const float* wc = wQKV + h * 96 * CD + c;
        #pragma unroll
        for (int d = 0; d < HD; ++d) {
            q[d]  = fmaf(xv, wc[d * CD], q[d]);
            kk[d] = fmaf(xv, wc[(32 + d) * CD], kk[d]);
            vv[d] = fmaf(xv, wc[(64 + d) * CD], vv[d]);
        }
    }
    float* kr = k_lds + (h * ST + l) * HD;
    float* vr = v_lds + (h * ST + l) * HD;
    #pragma unroll
    for (int d = 0; d < HD; ++d) { kr[d] = kk[d]; vr[d] = vv[d]; }
    __syncthreads();
    const float* kh2 = k_lds + h * ST * HD;
    const float* vh2 = v_lds + h * ST * HD;
    const int iq = l >> 3, jq = l & 7;
    float m = -1e30f;
    for (int sk = 0; sk < ST; ++sk) {
        const float* kp = kh2 + sk * HD;
        float a2 = 0.f;
        #pragma unroll
        for (int d = 0; d < HD; ++d) a2 = fmaf(q[d], kp[d], a2);
        int ridx = (iq - (sk >> 3) + 7) * 15 + (jq - (sk & 7) + 7);
        m = fmaxf(m, fmaf(a2, SCALE_, rpb[ridx * 4 + h]));
    }
    float o[HD];
    #pragma unroll
    for (int d = 0; d < HD; ++d) o[d] = 0.f;
    float ssum = 0.f;
    for (int sk = 0; sk < ST; ++sk) {
        const float* kp = kh2 + sk * HD;
        float a2 = 0.f;
        #pragma unroll
        for (int d = 0; d < HD; ++d) a2 = fmaf(q[d], kp[d], a2);
        int ridx = (iq - (sk >> 3) + 7) * 15 + (jq - (sk & 7) + 7);
        float e = __expf(fmaf(a2, SCALE_, rpb[ridx * 4 + h]) - m);
        ssum += e;
        const float* vp = vh2 + sk * HD;
        #pragma unroll
        for (int d = 0; d < HD; ++d) o[d] = fmaf(e, vp[d], o[d]);
    }
    const float inv = 1.f / ssum;
    __syncthreads();
    float* ot = k_lds;
    #pragma unroll
    for (int d = 0; d < HD; ++d) ot[(h * HD + d) * ST + l] = o[d] * inv;
    __syncthreads();
    float o2[HD];
    const float* pb2 = proj_b + h * HD;
    #pragma unroll
    for (int j = 0; j < HD; ++j) o2[j] = pb2[j];
    for (int c = 0; c < CD; ++c) {
        float xv = ot[c * ST + l];
        const float* pc = wP + h * HD * CD + c;
        #pragma unroll
        for (int j = 0; j < HD; ++j) o2[j] = fmaf(xv, pc[j * CD], o2[j]);
    }
    float* ob = out + pix;
    #pragma unroll
    for (int j = 0; j < HD; ++j) ob[(h * HD + j) * IMG] = o2[j];
}

extern "C" void kernel_launch(void* const* d_in, const int* in_sizes, int n_in,
                              void* d_out, int out_size, void* d_ws, size_t ws_size,
                              hipStream_t stream) {
    const float* x      = (const float*)d_in[0];
    const float* qkv_w  = (const float*)d_in[1];
    const float* qkv_b  = (const float*)d_in[2];
    const float* proj_w = (const float*)d_in[3];
    const float* proj_b = (const float*)d_in[4];
    const float* rpb    = (const float*)d_in[5];
    float* out = (float*)d_out;

    const int nW = 2 * 5 * 5 * 8 * 8;  // 3200 windows
    const size_t need = (size_t)(49152 + 16384) * sizeof(short);  // 128 KB

    if (ws_size >= need) {
        short* wq = (short*)d_ws;
        short* wp = wq + 49152;
        cvt_w_kernel<<<256, 256, 0, stream>>>(qkv_w, proj_w, wq, wp);
        win_attn_mfma<<<nW, 256, 0, stream>>>(x, wq, qkv_b, wp, proj_b, rpb, out);
    } else {
        win_attn_fallback<<<nW, 256, 0, stream>>>(x, qkv_w, qkv_b, proj_w, proj_b, rpb, out);
    }
}

// Round 4
// 298.519 us; speedup vs baseline: 3.1920x; 1.0533x over previous
//
#include <hip/hip_runtime.h>

#define NH 4
#define HD 32
#define ST 64          // tokens per window (8x8)
#define CD 128         // DIM
#define IMG 102400     // U*V*H*W
#define VHW 20480      // V*H*W
#define HW_ 4096       // H*W
#define SCALE_ 0.17677669529663687f   // 32^-0.5

typedef __attribute__((ext_vector_type(8))) short bf16x8;
typedef __attribute__((ext_vector_type(4))) float f32x4;

__device__ __forceinline__ short f2bf(float f) {
    unsigned int u = __float_as_uint(f);
    u = (u + 0x7FFF + ((u >> 16) & 1)) >> 16;   // RNE
    return (short)u;
}

// ---- fp32 -> bf16 weight conversion + dense bias table into workspace
__global__ void cvt_w_kernel(const float* __restrict__ qkv_w,
                             const float* __restrict__ proj_w,
                             const float* __restrict__ rpb,
                             short* __restrict__ wq,
                             short* __restrict__ wp,
                             float* __restrict__ bt) {
    int i = blockIdx.x * 256 + threadIdx.x;   // 81920 threads
    if (i < 49152) wq[i] = f2bf(qkv_w[i]);
    else if (i < 65536) wp[i - 49152] = f2bf(proj_w[i - 49152]);
    else if (i < 81920) {
        int j = i - 65536;                    // bt[h][q][k], 4*64*64
        int hh = j >> 12, q = (j >> 6) & 63, k = j & 63;
        int ridx = ((q >> 3) - (k >> 3) + 7) * 15 + ((q & 7) - (k & 7) + 7);
        bt[j] = rpb[ridx * 4 + hh];
    }
}

// LDS map (shorts; total 38400 = 75 KB):
//  X      [0, 8704)                 64 x 136  (tok-major, 128 ch + pad 8)
//  head h chunk at 8704 + h*5120:  Q_h [64][40], K_h [64][40]; P_h aliases (64x72)
//  V      [29184, 38400)            per head 32 x 72 (d-major)
//  O   aliases [0, 8704)            64 x 136  (after barrier; X dead)
//  F fp32 aliases [0, 17408 shorts) 128 x 68 floats (after proj-read barrier)

template <bool DB>   // DB: dense bias table available in ws
__global__ __launch_bounds__(256, 2)
void win_attn_mfma(const float* __restrict__ x,
                   const short* __restrict__ wq,     // bf16 [384][128]
                   const float* __restrict__ qkv_b,
                   const short* __restrict__ wp,     // bf16 [128][128]
                   const float* __restrict__ proj_b,
                   const float* __restrict__ bias,   // DB ? bt[4][64][64] : rpb
                   float* __restrict__ out) {
    __shared__ __align__(16) short smem[38400];

    const int t    = threadIdx.x;
    const int h    = __builtin_amdgcn_readfirstlane(t >> 6);  // wave = head
    const int ln   = t & 15;
    const int quad = (t >> 4) & 3;

    // gather/scatter mapping: s -> (row gr, 4-px group), cb -> channel block
    const int s    = t & 15;
    const int cb   = t >> 4;           // 0..15, channels cb*8 .. cb*8+7
    const int gr   = s >> 1;           // window row 0..7
    const int ghalf= s & 1;            // px group 0..1 (4 px each)

    // XCD swizzle: give each XCD 400 contiguous logical windows
    const int wid = (blockIdx.x & 7) * 400 + (blockIdx.x >> 3);
    const int wn = wid & 7, hn = (wid >> 3) & 7;
    int rem = wid >> 6;
    const int v = rem % 5; rem /= 5;
    const int u = rem % 5;
    const int b = rem / 5;

    // source pixels: shift by -4 mod 64; 4-px groups stay float4-aligned (4|shift)
    const int hh_r = (((hn << 3) + gr) - 4) & 63;
    const int ww0  = (((wn << 3) + ghalf * 4) - 4) & 63;
    const long pixrs = (long)b * (CD * IMG) + u * VHW + v * HW_ + hh_r * 64 + ww0;

    short* X  = smem;                      // [64][136]
    short* Qh = smem + 8704 + h * 5120;
    short* Kh = Qh + 2560;
    short* Ph = Qh;                        // aliases Q_h/K_h (in-wave only)
    short* Vh = smem + 29184 + h * 2304;   // [32][72]

    // ---- float4 gather: 8 vector loads/thread, all in flight ----
    float4 xv[8];
    #pragma unroll
    for (int j = 0; j < 8; ++j)
        xv[j] = *(const float4*)(x + pixrs + (long)(cb * 8 + j) * IMG);

    // ---- prefetch ALL QKV B-fragments (independent of X) ----
    bf16x8 wqf[24];
    #pragma unroll
    for (int kh = 0; kh < 4; ++kh)
        #pragma unroll
        for (int n = 0; n < 6; ++n)
            wqf[kh * 6 + n] = *(const bf16x8*)(wq + (h * 96 + n * 16 + ln) * 128 + kh * 32 + quad * 8);

    #pragma unroll
    for (int px = 0; px < 4; ++px) {
        bf16x8 pk;
        #pragma unroll
        for (int j = 0; j < 8; ++j) pk[j] = f2bf(((const float*)&xv[j])[px]);
        *(bf16x8*)(X + (gr * 8 + ghalf * 4 + px) * 136 + cb * 8) = pk;
    }
    __syncthreads();                       // barrier 1: X ready

    // ================= QKV GEMM: (64x128) @ (128x384)^T =================
    f32x4 acc[6][4];
    #pragma unroll
    for (int n = 0; n < 6; ++n)
        #pragma unroll
        for (int mt = 0; mt < 4; ++mt) acc[n][mt] = (f32x4){0.f, 0.f, 0.f, 0.f};

    #pragma unroll
    for (int kh = 0; kh < 4; ++kh) {
        bf16x8 af[4];
        #pragma unroll
        for (int mt = 0; mt < 4; ++mt)
            af[mt] = *(const bf16x8*)(X + (mt * 16 + ln) * 136 + kh * 32 + quad * 8);
        #pragma unroll
        for (int n = 0; n < 6; ++n)
            #pragma unroll
            for (int mt = 0; mt < 4; ++mt)
                acc[n][mt] = __builtin_amdgcn_mfma_f32_16x16x32_bf16(af[mt], wqf[kh * 6 + n], acc[n][mt], 0, 0, 0);
    }

    // D-tiles -> LDS: Q (scaled), K token-major; V d-major (transposed)
    #pragma unroll
    for (int n = 0; n < 6; ++n) {
        const float bias_v = qkv_b[h * 96 + n * 16 + ln];
        #pragma unroll
        for (int mt = 0; mt < 4; ++mt)
            #pragma unroll
            for (int r = 0; r < 4; ++r) {
                const float val = acc[n][mt][r] + bias_v;
                const int tk = mt * 16 + quad * 4 + r;
                if (n < 2)      Qh[tk * 40 + n * 16 + ln] = f2bf(val * SCALE_);
                else if (n < 4) Kh[tk * 40 + (n - 2) * 16 + ln] = f2bf(val);
                else            Vh[((n - 4) * 16 + ln) * 72 + tk] = f2bf(val);
            }
    }
    // Q/K/V/P strictly per-head, per-wave: no barrier until O overwrites X.

    // ================= S = Q K^T (64x64, K=32) =================
    bf16x8 aq[4], bk[4];
    #pragma unroll
    for (int mt = 0; mt < 4; ++mt) aq[mt] = *(const bf16x8*)(Qh + (mt * 16 + ln) * 40 + quad * 8);
    #pragma unroll
    for (int nt = 0; nt < 4; ++nt) bk[nt] = *(const bf16x8*)(Kh + (nt * 16 + ln) * 40 + quad * 8);
    f32x4 sm[4][4];
    #pragma unroll
    for (int mt = 0; mt < 4; ++mt)
        #pragma unroll
        for (int nt = 0; nt < 4; ++nt) {
            f32x4 z = (f32x4){0.f, 0.f, 0.f, 0.f};
            sm[mt][nt] = __builtin_amdgcn_mfma_f32_16x16x32_bf16(aq[mt], bk[nt], z, 0, 0, 0);
        }

    // relative-position bias
    if (DB) {
        const float* bt = bias + h * 4096;     // dense [64 q][64 k], coalesced
        #pragma unroll
        for (int mt = 0; mt < 4; ++mt)
            #pragma unroll
            for (int r = 0; r < 4; ++r) {
                const int qi = mt * 16 + quad * 4 + r;
                #pragma unroll
                for (int nt = 0; nt < 4; ++nt)
                    sm[mt][nt][r] += bt[qi * 64 + nt * 16 + ln];
            }
    } else {
        #pragma unroll
        for (int nt = 0; nt < 4; ++nt) {
            const int kcol = nt * 16 + ln;
            const int ik = kcol >> 3, jk = kcol & 7;
            #pragma unroll
            for (int mt = 0; mt < 4; ++mt)
                #pragma unroll
                for (int r = 0; r < 4; ++r) {
                    const int q = mt * 16 + quad * 4 + r;
                    const int ridx = ((q >> 3) - ik + 7) * 15 + ((q & 7) - jk + 7);
                    sm[mt][nt][r] += bias[ridx * 4 + h];
                }
        }
    }

    // softmax rows: row=(mt,r); cols span nt x 16 lanes of the quad
    float inv[4][4];
    #pragma unroll
    for (int mt = 0; mt < 4; ++mt)
        #pragma unroll
        for (int r = 0; r < 4; ++r) {
            float m = fmaxf(fmaxf(sm[mt][0][r], sm[mt][1][r]), fmaxf(sm[mt][2][r], sm[mt][3][r]));
            #pragma unroll
            for (int msk = 1; msk < 16; msk <<= 1) m = fmaxf(m, __shfl_xor(m, msk, 64));
            float sum = 0.f;
            #pragma unroll
            for (int nt = 0; nt < 4; ++nt) {
                float e = __expf(sm[mt][nt][r] - m);
                sm[mt][nt][r] = e;
                sum += e;
            }
            #pragma unroll
            for (int msk = 1; msk < 16; msk <<= 1) sum += __shfl_xor(sum, msk, 64);
            inv[mt][r] = 1.f / sum;
            const int q = mt * 16 + quad * 4 + r;
            #pragma unroll
            for (int nt = 0; nt < 4; ++nt)
                Ph[q * 72 + nt * 16 + ln] = f2bf(sm[mt][nt][r]);   // unnormalized P
        }

    // prefetch proj B-fragments during softmax slack
    bf16x8 wpf[8];
    #pragma unroll
    for (int kt = 0; kt < 4; ++kt)
        #pragma unroll
        for (int nt = 0; nt < 2; ++nt)
            wpf[kt * 2 + nt] = *(const bf16x8*)(wp + (h * 32 + nt * 16 + ln) * 128 + kt * 32 + quad * 8);

    // ================= O = P V (64x32, K=64) =================
    f32x4 oa[4][2];
    #pragma unroll
    for (int mt = 0; mt < 4; ++mt)
        #pragma unroll
        for (int nt = 0; nt < 2; ++nt) oa[mt][nt] = (f32x4){0.f, 0.f, 0.f, 0.f};
    #pragma unroll
    for (int kt = 0; kt < 2; ++kt) {
        bf16x8 ap[4], bv[2];
        #pragma unroll
        for (int mt = 0; mt < 4; ++mt)
            ap[mt] = *(const bf16x8*)(Ph + (mt * 16 + ln) * 72 + kt * 32 + quad * 8);
        #pragma unroll
        for (int nt = 0; nt < 2; ++nt)
            bv[nt] = *(const bf16x8*)(Vh + (nt * 16 + ln) * 72 + kt * 32 + quad * 8);
        #pragma unroll
        for (int mt = 0; mt < 4; ++mt)
            #pragma unroll
            for (int nt = 0; nt < 2; ++nt)
                oa[mt][nt] = __builtin_amdgcn_mfma_f32_16x16x32_bf16(ap[mt], bv[nt], oa[mt][nt], 0, 0, 0);
    }

    __syncthreads();              // barrier 2: all waves past X reads before O overwrite
    short* O = smem;              // [64][136]
    #pragma unroll
    for (int mt = 0; mt < 4; ++mt)
        #pragma unroll
        for (int nt = 0; nt < 2; ++nt)
            #pragma unroll
            for (int r = 0; r < 4; ++r)
                O[(mt * 16 + quad * 4 + r) * 136 + h * 32 + nt * 16 + ln] =
                    f2bf(oa[mt][nt][r] * inv[mt][r]);
    __syncthreads();              // barrier 3: O ready

    // ================= proj: (64x128) @ (128x128)^T =================
    f32x4 pa[4][2];
    #pragma unroll
    for (int mt = 0; mt < 4; ++mt)
        #pragma unroll
        for (int nt = 0; nt < 2; ++nt) pa[mt][nt] = (f32x4){0.f, 0.f, 0.f, 0.f};
    #pragma unroll
    for (int kt = 0; kt < 4; ++kt) {
        bf16x8 ao[4];
        #pragma unroll
        for (int mt = 0; mt < 4; ++mt)
            ao[mt] = *(const bf16x8*)(O + (mt * 16 + ln) * 136 + kt * 32 + quad * 8);
        #pragma unroll
        for (int mt = 0; mt < 4; ++mt)
            #pragma unroll
            for (int nt = 0; nt < 2; ++nt)
                pa[mt][nt] = __builtin_amdgcn_mfma_f32_16x16x32_bf16(ao[mt], wpf[kt * 2 + nt], pa[mt][nt], 0, 0, 0);
    }
    float pb[2];
    #pragma unroll
    for (int nt = 0; nt < 2; ++nt) pb[nt] = proj_b[h * 32 + nt * 16 + ln];

    __syncthreads();              // barrier 4: all proj A-frag reads done before F overwrites
    float* F = (float*)smem;      // [128][68]
    #pragma unroll
    for (int mt = 0; mt < 4; ++mt)
        #pragma unroll
        for (int nt = 0; nt < 2; ++nt)
            #pragma unroll
            for (int r = 0; r < 4; ++r)
                F[(h * 32 + nt * 16 + ln) * 68 + mt * 16 + quad * 4 + r] = pa[mt][nt][r] + pb[nt];
    __syncthreads();              // barrier 5: F ready

    // float4 scatter: 8 vector stores/thread (reverse shift == same pixels)
    #pragma unroll
    for (int j = 0; j < 8; ++j) {
        const int c = cb * 8 + j;
        float4 f4 = *(const float4*)(F + c * 68 + (gr * 8 + ghalf * 4));
        *(float4*)(out + pixrs + (long)c * IMG) = f4;
    }
}

// ---------- fp32 fallback (only if workspace is too small even for weights) ----------
__global__ __launch_bounds__(256, 1)
void win_attn_fallback(const float* __restrict__ x,
                       const float* __restrict__ wQKV,
                       const float* __restrict__ qkv_b,
                       const float* __restrict__ wP,
                       const float* __restrict__ proj_b,
                       const float* __restrict__ rpb,
                       float* __restrict__ out) {
    __shared__ __align__(16) float k_lds[NH * ST * HD];
    __shared__ __align__(16) float v_lds[NH * ST * HD];
    const int t = threadIdx.x;
    const int h = __builtin_amdgcn_readfirstlane(t >> 6);
    const int l = t & 63;
    const int wid = blockIdx.x;
    const int wn = wid & 7, hn = (wid >> 3) & 7;
    int rem = wid >> 6;
    const int v = rem % 5; rem /= 5;
    const int u = rem % 5;
    const int b = rem / 5;
    const int hh = (((hn << 3) + (l >> 3)) - 4) & 63;
    const int ww = (((wn << 3) + (l & 7)) - 4) & 63;
    const int pix = b * (NH * HD * IMG) + u * VHW + v * HW_ + hh * 64 + ww;
    float q[HD], kk[HD], vv[HD];
    const float* bq = qkv_b + h * 96;
    #pragma unroll
    for (int d = 0; d < HD; ++d) { q[d] = bq[d]; kk[d] = bq[32 + d]; vv[d] = bq[64 + d]; }
    for (int c = 0; c < CD; ++c) {
        float xv = x[pix + c * IMG];
        const float* wc = wQKV + h * 96 * CD + c;
        #pragma unroll
        for (int d = 0; d < HD; ++d) {
            q[d]  = fmaf(xv, wc[d * CD], q[d]);
            kk[d] = fmaf(xv, wc[(32 + d) * CD], kk[d]);
            vv[d] = fmaf(xv, wc[(64 + d) * CD], vv[d]);
        }
    }
    float* kr = k_lds + (h * ST + l) * HD;
    float* vr = v_lds + (h * ST + l) * HD;
    #pragma unroll
    for (int d = 0; d < HD; ++d) { kr[d] = kk[d]; vr[d] = vv[d]; }
    __syncthreads();
    const float* kh2 = k_lds + h * ST * HD;
    const float* vh2 = v_lds + h * ST * HD;
    const int iq = l >> 3, jq = l & 7;
    float m = -1e30f;
    for (int sk = 0; sk < ST; ++sk) {
        const float* kp = kh2 + sk * HD;
        float a2 = 0.f;
        #pragma unroll
        for (int d = 0; d < HD; ++d) a2 = fmaf(q[d], kp[d], a2);
        int ridx = (iq - (sk >> 3) + 7) * 15 + (jq - (sk & 7) + 7);
        m = fmaxf(m, fmaf(a2, SCALE_, rpb[ridx * 4 + h]));
    }
    float o[HD];
    #pragma unroll
    for (int d = 0; d < HD; ++d) o[d] = 0.f;
    float ssum = 0.f;
    for (int sk = 0; sk < ST; ++sk) {
        const float* kp = kh2 + sk * HD;
        float a2 = 0.f;
        #pragma unroll
        for (int d = 0; d < HD; ++d) a2 = fmaf(q[d], kp[d], a2);
        int ridx = (iq - (sk >> 3) + 7) * 15 + (jq - (sk & 7) + 7);
        float e = __expf(fmaf(a2, SCALE_, rpb[ridx * 4 + h]) - m);
        ssum += e;
        const float* vp = vh2 + sk * HD;
        #pragma unroll
        for (int d = 0; d < HD; ++d) o[d] = fmaf(e, vp[d], o[d]);
    }
    const float inv = 1.f / ssum;
    __syncthreads();
    float* ot = k_lds;
    #pragma unroll
    for (int d = 0; d < HD; ++d) ot[(h * HD + d) * ST + l] = o[d] * inv;
    __syncthreads();
    float o2[HD];
    const float* pb2 = proj_b + h * HD;
    #pragma unroll
    for (int j = 0; j < HD; ++j) o2[j] = pb2[j];
    for (int c = 0; c < CD; ++c) {
        float xv = ot[c * ST + l];
        const float* pc = wP + h * HD * CD + c;
        #pragma unroll
        for (int j = 0; j < HD; ++j) o2[j] = fmaf(xv, pc[j * CD], o2[j]);
    }
    float* ob = out + pix;
    #pragma unroll
    for (int j = 0; j < HD; ++j) ob[(h * HD + j) * IMG] = o2[j];
}

extern "C" void kernel_launch(void* const* d_in, const int* in_sizes, int n_in,
                              void* d_out, int out_size, void* d_ws, size_t ws_size,
                              hipStream_t stream) {
    const float* x      = (const float*)d_in[0];
    const float* qkv_w  = (const float*)d_in[1];
    const float* qkv_b  = (const float*)d_in[2];
    const float* proj_w = (const float*)d_in[3];
    const float* proj_b = (const float*)d_in[4];
    const float* rpb    = (const float*)d_in[5];
    float* out = (float*)d_out;

    const int nW = 2 * 5 * 5 * 8 * 8;  // 3200 windows
    const size_t need_w  = (size_t)(49152 + 16384) * sizeof(short);           // 128 KB
    const size_t need_db = need_w + (size_t)16384 * sizeof(float);            // +64 KB

    if (ws_size >= need_db) {
        short* wqs = (short*)d_ws;
        short* wps = wqs + 49152;
        float* bt  = (float*)(wqs + 65536);
        cvt_w_kernel<<<320, 256, 0, stream>>>(qkv_w, proj_w, rpb, wqs, wps, bt);
        win_attn_mfma<true><<<nW, 256, 0, stream>>>(x, wqs, qkv_b, wps, proj_b, bt, out);
    } else if (ws_size >= need_w) {
        short* wqs = (short*)d_ws;
        short* wps = wqs + 49152;
        cvt_w_kernel<<<256, 256, 0, stream>>>(qkv_w, proj_w, rpb, wqs, wps, nullptr);
        win_attn_mfma<false><<<nW, 256, 0, stream>>>(x, wqs, qkv_b, wps, proj_b, rpb, out);
    } else {
        win_attn_fallback<<<nW, 256, 0, stream>>>(x, qkv_w, qkv_b, proj_w, proj_b, rpb, out);
    }
}